// Round 14
// baseline (129.397 us; speedup 1.0000x reference)
//
#include <hip/hip_runtime.h>
#include <stdint.h>

typedef unsigned short ushort_t;
typedef __attribute__((ext_vector_type(8))) short short8;
typedef __attribute__((ext_vector_type(4))) float f32x4;
typedef __attribute__((ext_vector_type(4))) unsigned short ushort4v;

#define NBATCH 32
#define SEQ 1024
#define DIM 256
#define NH 8
#define ROWS (NBATCH * SEQ)   // 32768

__device__ __forceinline__ ushort_t f2bf(float f) {
    uint32_t u = __float_as_uint(f);
    u += 0x7fffu + ((u >> 16) & 1u);   // round-to-nearest-even
    return (ushort_t)(u >> 16);
}
__device__ __forceinline__ float bf2f(ushort_t h) {
    return __uint_as_float(((uint32_t)h) << 16);
}
__device__ __forceinline__ float exp2_fast(float x) {
    float r;
    asm("v_exp_f32 %0, %1" : "=v"(r) : "v"(x));
    return r;
}

typedef __attribute__((address_space(3))) void lds_void_t;
typedef const __attribute__((address_space(1))) void glob_void_t;
__device__ __forceinline__ void gld_lds16(const void* g, void* l) {
    __builtin_amdgcn_global_load_lds((glob_void_t*)g, (lds_void_t*)l, 16, 0, 0);
}

// ---------------------------------------------------------------------------
// Kernel 1: merged LN1 + weight prep (independent workloads, one launch).
// blocks [0, 8192): LayerNorm rows of x -> xn (bf16).
// blocks [8192, 9472): wT[n][k] = (bf16) w[k][n] for wq|wk|wv, wf1, wf2;
//   wq additionally scaled by log2(e) (softmax runs in exp2 domain).
// ---------------------------------------------------------------------------
__global__ __launch_bounds__(256) void ln1_prep(
    const float* __restrict__ x, const float* __restrict__ g,
    const float* __restrict__ beta, const float* __restrict__ wq,
    const float* __restrict__ wk, const float* __restrict__ wv,
    const float* __restrict__ wf1, const float* __restrict__ wf2,
    ushort_t* __restrict__ xn, ushort_t* __restrict__ wqkvT,
    ushort_t* __restrict__ wf1T, ushort_t* __restrict__ wf2T) {
    int blk = blockIdx.x;
    if (blk < 8192) {
        int wid = threadIdx.x >> 6, lane = threadIdx.x & 63;
        size_t row = (size_t)blk * 4 + wid;
        size_t base = row * 256 + lane * 4;
        float4 v = *(const float4*)(x + base);
        float s = v.x + v.y + v.z + v.w;
        float s2 = v.x * v.x + v.y * v.y + v.z * v.z + v.w * v.w;
#pragma unroll
        for (int msk = 1; msk < 64; msk <<= 1) {
            s += __shfl_xor(s, msk);
            s2 += __shfl_xor(s2, msk);
        }
        float mu = s * (1.f / 256.f);
        float var = s2 * (1.f / 256.f) - mu * mu;
        float rs = rsqrtf(var + 1e-5f);
        const float4 gv = *(const float4*)(g + lane * 4);
        const float4 bv = *(const float4*)(beta + lane * 4);
        ushort4v o;
        o[0] = f2bf((v.x - mu) * rs * gv.x + bv.x);
        o[1] = f2bf((v.y - mu) * rs * gv.y + bv.y);
        o[2] = f2bf((v.z - mu) * rs * gv.z + bv.z);
        o[3] = f2bf((v.w - mu) * rs * gv.w + bv.w);
        *(ushort4v*)(xn + base) = o;
    } else {
        int n = blk - 8192;
        int k = threadIdx.x;
        if (n < 768) {
            const float* w = (n < 256) ? wq : (n < 512 ? wk : wv);
            int nn = n & 255;
            float v = w[k * 256 + nn];
            if (n < 256) v *= 1.4426950408889634f;
            wqkvT[n * 256 + k] = f2bf(v);
        } else if (n < 1024) {
            int nn = n - 768;
            wf1T[nn * 256 + k] = f2bf(wf1[k * 256 + nn]);
        } else {
            int nn = n - 1024;
            wf2T[nn * 256 + k] = f2bf(wf2[k * 256 + nn]);
        }
    }
}

// ---------------------------------------------------------------------------
// Kernel 6: LayerNorm with +ctx residual (LN2)
// ---------------------------------------------------------------------------
__global__ __launch_bounds__(256) void ln2_kernel(
    const float* __restrict__ x, const ushort_t* __restrict__ ctx,
    const float* __restrict__ g, const float* __restrict__ beta,
    ushort_t* __restrict__ out) {
    int wid = threadIdx.x >> 6, lane = threadIdx.x & 63;
    size_t row = (size_t)blockIdx.x * 4 + wid;
    size_t base = row * 256 + lane * 4;
    float4 v = *(const float4*)(x + base);
    ushort4v c = *(const ushort4v*)(ctx + base);
    v.x += bf2f(c[0]); v.y += bf2f(c[1]);
    v.z += bf2f(c[2]); v.w += bf2f(c[3]);
    float s  = v.x + v.y + v.z + v.w;
    float s2 = v.x * v.x + v.y * v.y + v.z * v.z + v.w * v.w;
#pragma unroll
    for (int msk = 1; msk < 64; msk <<= 1) {
        s  += __shfl_xor(s, msk);
        s2 += __shfl_xor(s2, msk);
    }
    float mu  = s * (1.f / 256.f);
    float var = s2 * (1.f / 256.f) - mu * mu;
    float rs  = rsqrtf(var + 1e-5f);
    const float4 gv = *(const float4*)(g + lane * 4);
    const float4 bv = *(const float4*)(beta + lane * 4);
    ushort4v o;
    o[0] = f2bf((v.x - mu) * rs * gv.x + bv.x);
    o[1] = f2bf((v.y - mu) * rs * gv.y + bv.y);
    o[2] = f2bf((v.z - mu) * rs * gv.z + bv.z);
    o[3] = f2bf((v.w - mu) * rs * gv.w + bv.w);
    *(ushort4v*)(out + base) = o;
}

// ---------------------------------------------------------------------------
// Kernels 3/7/8: GEMM C[M x N] = A[M x 256] @ B^T[N x 256]^T   (bf16, fp32 acc)
// BK=64 (4 K-iters, 8 barriers vs 16 — short-K loops are barrier-drain-bound).
// Same k accumulation order as BK=32 -> bit-identical results.
// XCD-aware block swizzle (grid % 8 == 0 for all call sites).
// EPI: 0 = plain -> bf16 C
//      1 = +bias, relu -> bf16 (FFN1)
//      2 = +bias, +res -> f32  (FFN2 -> d_out)
//      3 = QKV with fragment-packed K/V epilogue (kpk/vpk blobs for attn's
//          coalesced 1KB wave-loads; sigma-permuted V, see R13).
// ---------------------------------------------------------------------------
template <int EPI>
__global__ __launch_bounds__(256) void gemm_bt(
    const ushort_t* __restrict__ A, const ushort_t* __restrict__ B,
    void* __restrict__ Cp, const float* __restrict__ bias,
    const ushort_t* __restrict__ res, ushort_t* __restrict__ kout,
    ushort_t* __restrict__ vout, int nbn, int ldc) {
    __shared__ ushort_t lds_a[8192];  // [128][64], 16 KB
    __shared__ ushort_t lds_b[8192];  // [128][64] (rows = output cols)
    int cpx = gridDim.x >> 3;
    int blk = (blockIdx.x & 7) * cpx + (blockIdx.x >> 3);
    int bn = blk % nbn, bm = blk / nbn;
    int m0 = bm * 128, n0 = bn * 128;
    int tid = threadIdx.x, wid = tid >> 6, lane = tid & 63;
    int fr = lane & 15, g = lane >> 4;
    int wm = (wid >> 1) * 64, wn = (wid & 1) * 64;

    f32x4 acc[4][4];
    const f32x4 fz = {0.f, 0.f, 0.f, 0.f};
#pragma unroll
    for (int m = 0; m < 4; m++)
#pragma unroll
        for (int n = 0; n < 4; n++) acc[m][n] = fz;

    for (int kt = 0; kt < 256; kt += 64) {
#pragma unroll
        for (int i = 0; i < 4; i++) {
            const ushort_t* as =
                A + (size_t)(m0 + i * 32 + (tid >> 3)) * 256 + kt + (tid & 7) * 8;
            gld_lds16(as, &lds_a[i * 2048 + wid * 512]);
            const ushort_t* bs =
                B + (size_t)(n0 + i * 32 + (tid >> 3)) * 256 + kt + (tid & 7) * 8;
            gld_lds16(bs, &lds_b[i * 2048 + wid * 512]);
        }
        __syncthreads();
#pragma unroll
        for (int s = 0; s < 2; s++) {
            short8 af[4], bfr[4];
#pragma unroll
            for (int m = 0; m < 4; m++)
                af[m] =
                    *(const short8*)&lds_a[(wm + m * 16 + fr) * 64 + s * 32 + g * 8];
#pragma unroll
            for (int n = 0; n < 4; n++)
                bfr[n] =
                    *(const short8*)&lds_b[(wn + n * 16 + fr) * 64 + s * 32 + g * 8];
#pragma unroll
            for (int m = 0; m < 4; m++)
#pragma unroll
                for (int n = 0; n < 4; n++)
                    acc[m][n] = __builtin_amdgcn_mfma_f32_16x16x32_bf16(
                        af[m], bfr[n], acc[m][n], 0, 0, 0);
        }
        __syncthreads();
    }

#pragma unroll
    for (int m = 0; m < 4; m++)
#pragma unroll
        for (int n = 0; n < 4; n++) {
            int col = n0 + wn + n * 16 + fr;
            int rowbase = m0 + wm + m * 16 + g * 4;
            if (EPI == 3 && col >= 512) {
                // V: fragment-packed, sigma-permuted (j=0..3 -> one 8B store)
                int hh = (col >> 5) & 7, hd = col & 31;
                int nn = hd >> 4, frv = hd & 15;
                int bb = rowbase >> 10;
                int key = rowbase & 1023;  // multiple of 4
                int slot0 = (key & ~31) + (((key & 15) >> 2) << 3) +
                            (((key >> 4) & 1) << 2);
                int t64 = slot0 >> 6, kk = (slot0 & 63) >> 5;
                int gv = (slot0 & 31) >> 3, e0 = slot0 & 7;
                ushort4v o;
                o[0] = f2bf(acc[m][n][0]);
                o[1] = f2bf(acc[m][n][1]);
                o[2] = f2bf(acc[m][n][2]);
                o[3] = f2bf(acc[m][n][3]);
                *(ushort4v*)(vout + (size_t)(bb * 8 + hh) * 32768 + t64 * 2048 +
                             (kk * 2 + nn) * 512 + (gv * 16 + frv) * 8 + e0) = o;
            } else if (EPI == 3 && col >= 256) {
                // K: fragment-packed scalar stores (16B apart across j)
                int hh = (col >> 5) & 7, hd = col & 31;
                int gk = hd >> 3, e = hd & 7;
                int bb = rowbase >> 10;
                int s = rowbase & 1023;  // key base; (s>>4) const across j
                size_t base = (size_t)(bb * 8 + hh) * 32768 + (s >> 4) * 512 +
                              gk * 128 + e;
#pragma unroll
                for (int j = 0; j < 4; j++)
                    kout[base + ((s & 15) + j) * 8] = f2bf(acc[m][n][j]);
            } else {
                float bv = (EPI == 1 || EPI == 2) ? bias[col] : 0.f;
#pragma unroll
                for (int j = 0; j < 4; j++) {
                    size_t row = (size_t)(rowbase + j);
                    float v = acc[m][n][j] + bv;
                    if (EPI == 1) v = fmaxf(v, 0.f);
                    if (EPI == 2) {
                        v += bf2f(res[row * 256 + col]);
                        ((float*)Cp)[row * ldc + col] = v;
                    } else {
                        ((ushort_t*)Cp)[row * ldc + col] = f2bf(v);
                    }
                }
            }
        }
}

// ---------------------------------------------------------------------------
// Kernel 5: flash attention, swapped-QK^T, zero LDS, branch-free & shfl-free.
// FROZEN at R13 text (4 data-movement restructures NaN'd; address-only
// changes proven safe). K/V from fragment-packed blobs: every wave-load is
// one contiguous 1KB segment (base + lane*16B).
// ---------------------------------------------------------------------------
__global__ __launch_bounds__(256, 4) void attn_kernel(
    const ushort_t* __restrict__ q, const ushort_t* __restrict__ kpk,
    const ushort_t* __restrict__ vpk, ushort_t* __restrict__ ctx) {
    int cpx = gridDim.x >> 3;
    int wgid = (blockIdx.x & 7) * cpx + (blockIdx.x >> 3);
    int bh = wgid >> 3, qt = wgid & 7;
    int b = bh >> 3, h = bh & 7;
    int tid = threadIdx.x, wid = tid >> 6, lane = tid & 63;
    int fr = lane & 15, g = lane >> 4;
    int q0 = qt * 128 + wid * 32;
    const ushort_t* qbase = q + (size_t)b * SEQ * 256;
    const ushort_t* kpb = kpk + (size_t)bh * 32768;
    const ushort_t* vpb = vpk + (size_t)bh * 32768;
    const int l8 = lane * 8;

    // Q fragments (B operand of swapped QK^T); Q pre-scaled by log2(e)
    short8 qb[2];
#pragma unroll
    for (int m = 0; m < 2; m++)
        qb[m] = *(const short8*)(qbase + (size_t)(q0 + m * 16 + fr) * 256 +
                                 h * 32 + g * 8);

    f32x4 acc[2][2], asum[2];
    const f32x4 fz = {0.f, 0.f, 0.f, 0.f};
#pragma unroll
    for (int m = 0; m < 2; m++) {
        acc[m][0] = fz;
        acc[m][1] = fz;
        asum[m] = fz;
    }
    // all-ones bf16 B-fragment for the row-sum MFMA
    short8 ones8;
#pragma unroll
    for (int i = 0; i < 8; i++) ones8[i] = (short)0x3f80;

    // prefetch first K tile (64 keys = 4 fragments; coalesced 1KB each)
    short8 kreg[4];
#pragma unroll
    for (int n = 0; n < 4; n++)
        kreg[n] = *(const short8*)(kpb + n * 512 + l8);

    for (int kv = 0; kv < SEQ; kv += 64) {
        // ---- issue V loads for this tile (coalesced; in flight through QK)
        short8 vreg[2][2];
#pragma unroll
        for (int kk = 0; kk < 2; kk++) {
            vreg[kk][0] =
                *(const short8*)(vpb + (kv >> 6) * 2048 + (kk * 2) * 512 + l8);
            vreg[kk][1] = *(const short8*)(vpb + (kv >> 6) * 2048 +
                                           (kk * 2 + 1) * 512 + l8);
        }

        // ---- scores (log2 domain): s[n][m][j] = S[key=n*16+g*4+j][q=m*16+fr]
        f32x4 s[4][2];
#pragma unroll
        for (int n = 0; n < 4; n++)
#pragma unroll
            for (int m = 0; m < 2; m++)
                s[n][m] = __builtin_amdgcn_mfma_f32_16x16x32_bf16(kreg[n], qb[m],
                                                                  fz, 0, 0, 0);

        // ---- prefetch next K tile (completes during exp + PV)
        if (kv + 64 < SEQ) {
#pragma unroll
            for (int n = 0; n < 4; n++)
                kreg[n] = *(const short8*)(kpb + ((kv + 64) >> 4) * 512 +
                                           n * 512 + l8);
        }

        // ---- P = exp2(s), pack to bf16 in-lane, PV + ones-column row-sum
#pragma unroll
        for (int kk = 0; kk < 2; kk++) {
#pragma unroll
            for (int m = 0; m < 2; m++) {
                float p0 = exp2_fast(s[2 * kk][m][0]);
                float p1 = exp2_fast(s[2 * kk][m][1]);
                float p2 = exp2_fast(s[2 * kk][m][2]);
                float p3 = exp2_fast(s[2 * kk][m][3]);
                float p4 = exp2_fast(s[2 * kk + 1][m][0]);
                float p5 = exp2_fast(s[2 * kk + 1][m][1]);
                float p6 = exp2_fast(s[2 * kk + 1][m][2]);
                float p7 = exp2_fast(s[2 * kk + 1][m][3]);
                union { short8 s8; uint32_t u[4]; } pa;
                asm("v_cvt_pk_bf16_f32 %0, %1, %2"
                    : "=v"(pa.u[0]) : "v"(p0), "v"(p1));
                asm("v_cvt_pk_bf16_f32 %0, %1, %2"
                    : "=v"(pa.u[1]) : "v"(p2), "v"(p3));
                asm("v_cvt_pk_bf16_f32 %0, %1, %2"
                    : "=v"(pa.u[2]) : "v"(p4), "v"(p5));
                asm("v_cvt_pk_bf16_f32 %0, %1, %2"
                    : "=v"(pa.u[3]) : "v"(p6), "v"(p7));
                acc[m][0] = __builtin_amdgcn_mfma_f32_16x16x32_bf16(
                    pa.s8, vreg[kk][0], acc[m][0], 0, 0, 0);
                acc[m][1] = __builtin_amdgcn_mfma_f32_16x16x32_bf16(
                    pa.s8, vreg[kk][1], acc[m][1], 0, 0, 0);
                asum[m] = __builtin_amdgcn_mfma_f32_16x16x32_bf16(
                    pa.s8, ones8, asum[m], 0, 0, 0);
            }
        }
    }

    // ---- epilogue: lane (fr,g) holds ctx[q=m*16+g*4+j][hd=n*16+fr];
    //      asum[m][j] is the matching row sum (same D layout) -> no shfl.
#pragma unroll
    for (int m = 0; m < 2; m++)
#pragma unroll
        for (int j = 0; j < 4; j++) {
            float inv = 1.f / asum[m][j];
#pragma unroll
            for (int n = 0; n < 2; n++) {
                size_t row = (size_t)b * SEQ + q0 + m * 16 + g * 4 + j;
                ctx[row * 256 + h * 32 + n * 16 + fr] =
                    f2bf(acc[m][n][j] * inv);
            }
        }
}

// ---------------------------------------------------------------------------
extern "C" void kernel_launch(void* const* d_in, const int* in_sizes, int n_in,
                              void* d_out, int out_size, void* d_ws,
                              size_t ws_size, hipStream_t stream) {
    const float* x   = (const float*)d_in[0];
    const float* wq  = (const float*)d_in[1];
    const float* wk  = (const float*)d_in[2];
    const float* wv  = (const float*)d_in[3];
    const float* g1  = (const float*)d_in[4];
    const float* be1 = (const float*)d_in[5];
    const float* g2  = (const float*)d_in[6];
    const float* be2 = (const float*)d_in[7];
    const float* wf1 = (const float*)d_in[8];
    const float* bf1 = (const float*)d_in[9];
    const float* wf2 = (const float*)d_in[10];
    const float* bf2 = (const float*)d_in[11];

    char* ws = (char*)d_ws;
    const size_t SZ16M = (size_t)ROWS * 256 * 2;  // 16 MiB
    ushort_t* wqkvT = (ushort_t*)(ws);                      // 768*256*2
    ushort_t* wf1T  = (ushort_t*)(ws + 393216);
    ushort_t* wf2T  = (ushort_t*)(ws + 524288);
    ushort_t* xn    = (ushort_t*)(ws + 655360);             // 16 MiB (reused as h)
    ushort_t* qonly = (ushort_t*)(ws + 655360 + SZ16M);     // 16 MiB
    ushort_t* kpk   = (ushort_t*)(ws + 655360 + 2 * SZ16M); // 16 MiB
    ushort_t* vpk   = (ushort_t*)(ws + 655360 + 3 * SZ16M); // 16 MiB
    ushort_t* ctxb  = (ushort_t*)(ws + 655360 + 4 * SZ16M); // 16 MiB
    ushort_t* ab    = (ushort_t*)(ws + 655360 + 5 * SZ16M); // 16 MiB
    ushort_t* hb    = xn;  // xn dead after QKV GEMM

    ln1_prep<<<dim3(9472), dim3(256), 0, stream>>>(
        x, g1, be1, wq, wk, wv, wf1, wf2, xn, wqkvT, wf1T, wf2T);
    gemm_bt<3><<<dim3(256 * 6), dim3(256), 0, stream>>>(
        xn, wqkvT, (void*)qonly, nullptr, nullptr, kpk, vpk, 6, 256);
    attn_kernel<<<dim3(2048), dim3(256), 0, stream>>>(qonly, kpk, vpk, ctxb);
    ln2_kernel<<<dim3(ROWS / 4), dim3(256), 0, stream>>>(x, ctxb, g2, be2, ab);
    gemm_bt<1><<<dim3(256 * 2), dim3(256), 0, stream>>>(
        ab, wf1T, (void*)hb, bf1, nullptr, nullptr, nullptr, 2, 256);
    gemm_bt<2><<<dim3(256 * 2), dim3(256), 0, stream>>>(
        hb, wf2T, d_out, bf2, ab, nullptr, nullptr, 2, 256);
}

// Round 15
// 118.260 us; speedup vs baseline: 1.0942x; 1.0942x over previous
//
#include <hip/hip_runtime.h>
#include <stdint.h>

typedef unsigned short ushort_t;
typedef __attribute__((ext_vector_type(8))) short short8;
typedef __attribute__((ext_vector_type(4))) float f32x4;
typedef __attribute__((ext_vector_type(4))) unsigned short ushort4v;

#define NBATCH 32
#define SEQ 1024
#define DIM 256
#define NH 8
#define ROWS (NBATCH * SEQ)   // 32768

__device__ __forceinline__ ushort_t f2bf(float f) {
    uint32_t u = __float_as_uint(f);
    u += 0x7fffu + ((u >> 16) & 1u);   // round-to-nearest-even
    return (ushort_t)(u >> 16);
}
__device__ __forceinline__ float bf2f(ushort_t h) {
    return __uint_as_float(((uint32_t)h) << 16);
}
__device__ __forceinline__ float exp2_fast(float x) {
    float r;
    asm("v_exp_f32 %0, %1" : "=v"(r) : "v"(x));
    return r;
}

typedef __attribute__((address_space(3))) void lds_void_t;
typedef const __attribute__((address_space(1))) void glob_void_t;
__device__ __forceinline__ void gld_lds16(const void* g, void* l) {
    __builtin_amdgcn_global_load_lds((glob_void_t*)g, (lds_void_t*)l, 16, 0, 0);
}

// ---------------------------------------------------------------------------
// Kernel 1: merged LN1 + weight prep (independent workloads, one launch).
// blocks [0, 8192): LayerNorm rows of x -> xn (bf16).
// blocks [8192, 9472): wT[n][k] = (bf16) w[k][n] for wq|wk|wv, wf1, wf2;
//   wq additionally scaled by log2(e) (softmax runs in exp2 domain).
// ---------------------------------------------------------------------------
__global__ __launch_bounds__(256) void ln1_prep(
    const float* __restrict__ x, const float* __restrict__ g,
    const float* __restrict__ beta, const float* __restrict__ wq,
    const float* __restrict__ wk, const float* __restrict__ wv,
    const float* __restrict__ wf1, const float* __restrict__ wf2,
    ushort_t* __restrict__ xn, ushort_t* __restrict__ wqkvT,
    ushort_t* __restrict__ wf1T, ushort_t* __restrict__ wf2T) {
    int blk = blockIdx.x;
    if (blk < 8192) {
        int wid = threadIdx.x >> 6, lane = threadIdx.x & 63;
        size_t row = (size_t)blk * 4 + wid;
        size_t base = row * 256 + lane * 4;
        float4 v = *(const float4*)(x + base);
        float s = v.x + v.y + v.z + v.w;
        float s2 = v.x * v.x + v.y * v.y + v.z * v.z + v.w * v.w;
#pragma unroll
        for (int msk = 1; msk < 64; msk <<= 1) {
            s += __shfl_xor(s, msk);
            s2 += __shfl_xor(s2, msk);
        }
        float mu = s * (1.f / 256.f);
        float var = s2 * (1.f / 256.f) - mu * mu;
        float rs = rsqrtf(var + 1e-5f);
        const float4 gv = *(const float4*)(g + lane * 4);
        const float4 bv = *(const float4*)(beta + lane * 4);
        ushort4v o;
        o[0] = f2bf((v.x - mu) * rs * gv.x + bv.x);
        o[1] = f2bf((v.y - mu) * rs * gv.y + bv.y);
        o[2] = f2bf((v.z - mu) * rs * gv.z + bv.z);
        o[3] = f2bf((v.w - mu) * rs * gv.w + bv.w);
        *(ushort4v*)(xn + base) = o;
    } else {
        int n = blk - 8192;
        int k = threadIdx.x;
        if (n < 768) {
            const float* w = (n < 256) ? wq : (n < 512 ? wk : wv);
            int nn = n & 255;
            float v = w[k * 256 + nn];
            if (n < 256) v *= 1.4426950408889634f;
            wqkvT[n * 256 + k] = f2bf(v);
        } else if (n < 1024) {
            int nn = n - 768;
            wf1T[nn * 256 + k] = f2bf(wf1[k * 256 + nn]);
        } else {
            int nn = n - 1024;
            wf2T[nn * 256 + k] = f2bf(wf2[k * 256 + nn]);
        }
    }
}

// ---------------------------------------------------------------------------
// Kernel 6: LayerNorm with +ctx residual (LN2)
// ---------------------------------------------------------------------------
__global__ __launch_bounds__(256) void ln2_kernel(
    const float* __restrict__ x, const ushort_t* __restrict__ ctx,
    const float* __restrict__ g, const float* __restrict__ beta,
    ushort_t* __restrict__ out) {
    int wid = threadIdx.x >> 6, lane = threadIdx.x & 63;
    size_t row = (size_t)blockIdx.x * 4 + wid;
    size_t base = row * 256 + lane * 4;
    float4 v = *(const float4*)(x + base);
    ushort4v c = *(const ushort4v*)(ctx + base);
    v.x += bf2f(c[0]); v.y += bf2f(c[1]);
    v.z += bf2f(c[2]); v.w += bf2f(c[3]);
    float s  = v.x + v.y + v.z + v.w;
    float s2 = v.x * v.x + v.y * v.y + v.z * v.z + v.w * v.w;
#pragma unroll
    for (int msk = 1; msk < 64; msk <<= 1) {
        s  += __shfl_xor(s, msk);
        s2 += __shfl_xor(s2, msk);
    }
    float mu  = s * (1.f / 256.f);
    float var = s2 * (1.f / 256.f) - mu * mu;
    float rs  = rsqrtf(var + 1e-5f);
    const float4 gv = *(const float4*)(g + lane * 4);
    const float4 bv = *(const float4*)(beta + lane * 4);
    ushort4v o;
    o[0] = f2bf((v.x - mu) * rs * gv.x + bv.x);
    o[1] = f2bf((v.y - mu) * rs * gv.y + bv.y);
    o[2] = f2bf((v.z - mu) * rs * gv.z + bv.z);
    o[3] = f2bf((v.w - mu) * rs * gv.w + bv.w);
    *(ushort4v*)(out + base) = o;
}

// ---------------------------------------------------------------------------
// Kernel 3: QKV GEMM (R13 text, BK=32 — R14's BK=64 regressed, reverted).
// C[M x N] = A[M x 256] @ B^T[N x 256]^T  (bf16, fp32 acc), XCD swizzle.
// EPI=3: Q -> Cp (ldc=256); K/V -> fragment-packed kpk/vpk blobs so attn's
// wave-loads are single coalesced 1KB segments (sigma-permuted V, see R13).
// ---------------------------------------------------------------------------
template <int EPI>
__global__ __launch_bounds__(256) void gemm_bt(
    const ushort_t* __restrict__ A, const ushort_t* __restrict__ B,
    void* __restrict__ Cp, const float* __restrict__ bias,
    const ushort_t* __restrict__ res, ushort_t* __restrict__ kout,
    ushort_t* __restrict__ vout, int nbn, int ldc) {
    __shared__ ushort_t lds_a[4096];  // [128][32]
    __shared__ ushort_t lds_b[4096];  // [128][32] (rows = output cols)
    int cpx = gridDim.x >> 3;
    int blk = (blockIdx.x & 7) * cpx + (blockIdx.x >> 3);
    int bn = blk % nbn, bm = blk / nbn;
    int m0 = bm * 128, n0 = bn * 128;
    int tid = threadIdx.x, wid = tid >> 6, lane = tid & 63;
    int fr = lane & 15, g = lane >> 4;
    int wm = (wid >> 1) * 64, wn = (wid & 1) * 64;

    f32x4 acc[4][4];
    const f32x4 fz = {0.f, 0.f, 0.f, 0.f};
#pragma unroll
    for (int m = 0; m < 4; m++)
#pragma unroll
        for (int n = 0; n < 4; n++) acc[m][n] = fz;

    for (int kt = 0; kt < 256; kt += 32) {
#pragma unroll
        for (int i = 0; i < 2; i++) {
            const ushort_t* as =
                A + (size_t)(m0 + i * 64 + (tid >> 2)) * 256 + kt + (tid & 3) * 8;
            gld_lds16(as, &lds_a[i * 2048 + wid * 512]);
            const ushort_t* bs =
                B + (size_t)(n0 + i * 64 + (tid >> 2)) * 256 + kt + (tid & 3) * 8;
            gld_lds16(bs, &lds_b[i * 2048 + wid * 512]);
        }
        __syncthreads();
        short8 af[4], bfr[4];
#pragma unroll
        for (int m = 0; m < 4; m++)
            af[m] = *(const short8*)&lds_a[(wm + m * 16 + fr) * 32 + g * 8];
#pragma unroll
        for (int n = 0; n < 4; n++)
            bfr[n] = *(const short8*)&lds_b[(wn + n * 16 + fr) * 32 + g * 8];
#pragma unroll
        for (int m = 0; m < 4; m++)
#pragma unroll
            for (int n = 0; n < 4; n++)
                acc[m][n] = __builtin_amdgcn_mfma_f32_16x16x32_bf16(
                    af[m], bfr[n], acc[m][n], 0, 0, 0);
        __syncthreads();
    }

#pragma unroll
    for (int m = 0; m < 4; m++)
#pragma unroll
        for (int n = 0; n < 4; n++) {
            int col = n0 + wn + n * 16 + fr;
            int rowbase = m0 + wm + m * 16 + g * 4;
            if (EPI == 3 && col >= 512) {
                // V: fragment-packed, sigma-permuted (j=0..3 -> one 8B store)
                int hh = (col >> 5) & 7, hd = col & 31;
                int nn = hd >> 4, frv = hd & 15;
                int bb = rowbase >> 10;
                int key = rowbase & 1023;  // multiple of 4
                int slot0 = (key & ~31) + (((key & 15) >> 2) << 3) +
                            (((key >> 4) & 1) << 2);
                int t64 = slot0 >> 6, kk = (slot0 & 63) >> 5;
                int gv = (slot0 & 31) >> 3, e0 = slot0 & 7;
                ushort4v o;
                o[0] = f2bf(acc[m][n][0]);
                o[1] = f2bf(acc[m][n][1]);
                o[2] = f2bf(acc[m][n][2]);
                o[3] = f2bf(acc[m][n][3]);
                *(ushort4v*)(vout + (size_t)(bb * 8 + hh) * 32768 + t64 * 2048 +
                             (kk * 2 + nn) * 512 + (gv * 16 + frv) * 8 + e0) = o;
            } else if (EPI == 3 && col >= 256) {
                // K: fragment-packed scalar stores (16B apart across j)
                int hh = (col >> 5) & 7, hd = col & 31;
                int gk = hd >> 3, e = hd & 7;
                int bb = rowbase >> 10;
                int s = rowbase & 1023;  // key base; (s>>4) const across j
                size_t base = (size_t)(bb * 8 + hh) * 32768 + (s >> 4) * 512 +
                              gk * 128 + e;
#pragma unroll
                for (int j = 0; j < 4; j++)
                    kout[base + ((s & 15) + j) * 8] = f2bf(acc[m][n][j]);
            } else {
                float bv = (EPI == 1 || EPI == 2) ? bias[col] : 0.f;
#pragma unroll
                for (int j = 0; j < 4; j++) {
                    size_t row = (size_t)(rowbase + j);
                    float v = acc[m][n][j] + bv;
                    if (EPI == 1) v = fmaxf(v, 0.f);
                    if (EPI == 2) {
                        v += bf2f(res[row * 256 + col]);
                        ((float*)Cp)[row * ldc + col] = v;
                    } else {
                        ((ushort_t*)Cp)[row * ldc + col] = f2bf(v);
                    }
                }
            }
        }
}

// ---------------------------------------------------------------------------
// Kernel 7: fused FFN — out = a + relu(a@W1+b1)@W2 + b2, one 64-row stripe
// per block. Phase 1 keeps h_tile in padded LDS ([64][264]: stride 528B ->
// 2-way max on phase-2 reads); phase 2 consumes it as the A-operand.
// Eliminates h's 32MB global round-trip + the ab re-read + one launch.
// Built from the verified gemm_bt tile/staging pattern (BK=32).
// ---------------------------------------------------------------------------
__global__ __launch_bounds__(256) void ffn_fused(
    const ushort_t* __restrict__ A, const ushort_t* __restrict__ W1,
    const ushort_t* __restrict__ W2, const float* __restrict__ b1,
    const float* __restrict__ b2, float* __restrict__ out) {
    __shared__ ushort_t a_lds[64 * 32];    //  4 KB
    __shared__ ushort_t w_lds[256 * 32];   // 16 KB (W1 then W2 staging)
    __shared__ ushort_t h_lds[64 * 264];   // 33 KB padded
    int m0 = blockIdx.x * 64;
    int tid = threadIdx.x, wid = tid >> 6, lane = tid & 63;
    int fr = lane & 15, g = lane >> 4;
    int wn = wid * 64;  // this wave's output-column block (both phases)

    f32x4 acc[4][4];
    const f32x4 fz = {0.f, 0.f, 0.f, 0.f};
#pragma unroll
    for (int m = 0; m < 4; m++)
#pragma unroll
        for (int n = 0; n < 4; n++) acc[m][n] = fz;

    // ---------------- phase 1: h = relu(a @ W1^T + b1) -> h_lds ----------
    for (int kt = 0; kt < 256; kt += 32) {
        gld_lds16(A + (size_t)(m0 + (tid >> 2)) * 256 + kt + (tid & 3) * 8,
                  &a_lds[wid * 512]);
#pragma unroll
        for (int i = 0; i < 4; i++)
            gld_lds16(W1 + (size_t)(i * 64 + (tid >> 2)) * 256 + kt +
                          (tid & 3) * 8,
                      &w_lds[i * 2048 + wid * 512]);
        __syncthreads();
        short8 af[4], bfr[4];
#pragma unroll
        for (int m = 0; m < 4; m++)
            af[m] = *(const short8*)&a_lds[(m * 16 + fr) * 32 + g * 8];
#pragma unroll
        for (int n = 0; n < 4; n++)
            bfr[n] = *(const short8*)&w_lds[(wn + n * 16 + fr) * 32 + g * 8];
#pragma unroll
        for (int m = 0; m < 4; m++)
#pragma unroll
            for (int n = 0; n < 4; n++)
                acc[m][n] = __builtin_amdgcn_mfma_f32_16x16x32_bf16(
                    af[m], bfr[n], acc[m][n], 0, 0, 0);
        __syncthreads();
    }
#pragma unroll
    for (int m = 0; m < 4; m++)
#pragma unroll
        for (int n = 0; n < 4; n++) {
            int col = wn + n * 16 + fr;
            float bv = b1[col];
#pragma unroll
            for (int j = 0; j < 4; j++) {
                int row = m * 16 + g * 4 + j;
                h_lds[row * 264 + col] = f2bf(fmaxf(acc[m][n][j] + bv, 0.f));
            }
            acc[m][n] = fz;  // re-zero for phase 2
        }
    __syncthreads();

    // ---------------- phase 2: out = a + h @ W2^T + b2 --------------------
    for (int kt = 0; kt < 256; kt += 32) {
#pragma unroll
        for (int i = 0; i < 4; i++)
            gld_lds16(W2 + (size_t)(i * 64 + (tid >> 2)) * 256 + kt +
                          (tid & 3) * 8,
                      &w_lds[i * 2048 + wid * 512]);
        __syncthreads();
        short8 af[4], bfr[4];
#pragma unroll
        for (int m = 0; m < 4; m++)
            af[m] = *(const short8*)&h_lds[(m * 16 + fr) * 264 + kt + g * 8];
#pragma unroll
        for (int n = 0; n < 4; n++)
            bfr[n] = *(const short8*)&w_lds[(wn + n * 16 + fr) * 32 + g * 8];
#pragma unroll
        for (int m = 0; m < 4; m++)
#pragma unroll
            for (int n = 0; n < 4; n++)
                acc[m][n] = __builtin_amdgcn_mfma_f32_16x16x32_bf16(
                    af[m], bfr[n], acc[m][n], 0, 0, 0);
        __syncthreads();
    }
#pragma unroll
    for (int m = 0; m < 4; m++)
#pragma unroll
        for (int n = 0; n < 4; n++) {
            int col = wn + n * 16 + fr;
            float bv = b2[col];
#pragma unroll
            for (int j = 0; j < 4; j++) {
                size_t row = (size_t)(m0 + m * 16 + g * 4 + j);
                out[row * 256 + col] =
                    acc[m][n][j] + bv + bf2f(A[row * 256 + col]);
            }
        }
}

// ---------------------------------------------------------------------------
// Kernel 5: flash attention, swapped-QK^T, zero LDS, branch-free & shfl-free.
// FROZEN at R13 text (4 data-movement restructures NaN'd; address-only
// changes proven safe). K/V from fragment-packed blobs: every wave-load is
// one contiguous 1KB segment (base + lane*16B).
// ---------------------------------------------------------------------------
__global__ __launch_bounds__(256, 4) void attn_kernel(
    const ushort_t* __restrict__ q, const ushort_t* __restrict__ kpk,
    const ushort_t* __restrict__ vpk, ushort_t* __restrict__ ctx) {
    int cpx = gridDim.x >> 3;
    int wgid = (blockIdx.x & 7) * cpx + (blockIdx.x >> 3);
    int bh = wgid >> 3, qt = wgid & 7;
    int b = bh >> 3, h = bh & 7;
    int tid = threadIdx.x, wid = tid >> 6, lane = tid & 63;
    int fr = lane & 15, g = lane >> 4;
    int q0 = qt * 128 + wid * 32;
    const ushort_t* qbase = q + (size_t)b * SEQ * 256;
    const ushort_t* kpb = kpk + (size_t)bh * 32768;
    const ushort_t* vpb = vpk + (size_t)bh * 32768;
    const int l8 = lane * 8;

    // Q fragments (B operand of swapped QK^T); Q pre-scaled by log2(e)
    short8 qb[2];
#pragma unroll
    for (int m = 0; m < 2; m++)
        qb[m] = *(const short8*)(qbase + (size_t)(q0 + m * 16 + fr) * 256 +
                                 h * 32 + g * 8);

    f32x4 acc[2][2], asum[2];
    const f32x4 fz = {0.f, 0.f, 0.f, 0.f};
#pragma unroll
    for (int m = 0; m < 2; m++) {
        acc[m][0] = fz;
        acc[m][1] = fz;
        asum[m] = fz;
    }
    // all-ones bf16 B-fragment for the row-sum MFMA
    short8 ones8;
#pragma unroll
    for (int i = 0; i < 8; i++) ones8[i] = (short)0x3f80;

    // prefetch first K tile (64 keys = 4 fragments; coalesced 1KB each)
    short8 kreg[4];
#pragma unroll
    for (int n = 0; n < 4; n++)
        kreg[n] = *(const short8*)(kpb + n * 512 + l8);

    for (int kv = 0; kv < SEQ; kv += 64) {
        // ---- issue V loads for this tile (coalesced; in flight through QK)
        short8 vreg[2][2];
#pragma unroll
        for (int kk = 0; kk < 2; kk++) {
            vreg[kk][0] =
                *(const short8*)(vpb + (kv >> 6) * 2048 + (kk * 2) * 512 + l8);
            vreg[kk][1] = *(const short8*)(vpb + (kv >> 6) * 2048 +
                                           (kk * 2 + 1) * 512 + l8);
        }

        // ---- scores (log2 domain): s[n][m][j] = S[key=n*16+g*4+j][q=m*16+fr]
        f32x4 s[4][2];
#pragma unroll
        for (int n = 0; n < 4; n++)
#pragma unroll
            for (int m = 0; m < 2; m++)
                s[n][m] = __builtin_amdgcn_mfma_f32_16x16x32_bf16(kreg[n], qb[m],
                                                                  fz, 0, 0, 0);

        // ---- prefetch next K tile (completes during exp + PV)
        if (kv + 64 < SEQ) {
#pragma unroll
            for (int n = 0; n < 4; n++)
                kreg[n] = *(const short8*)(kpb + ((kv + 64) >> 4) * 512 +
                                           n * 512 + l8);
        }

        // ---- P = exp2(s), pack to bf16 in-lane, PV + ones-column row-sum
#pragma unroll
        for (int kk = 0; kk < 2; kk++) {
#pragma unroll
            for (int m = 0; m < 2; m++) {
                float p0 = exp2_fast(s[2 * kk][m][0]);
                float p1 = exp2_fast(s[2 * kk][m][1]);
                float p2 = exp2_fast(s[2 * kk][m][2]);
                float p3 = exp2_fast(s[2 * kk][m][3]);
                float p4 = exp2_fast(s[2 * kk + 1][m][0]);
                float p5 = exp2_fast(s[2 * kk + 1][m][1]);
                float p6 = exp2_fast(s[2 * kk + 1][m][2]);
                float p7 = exp2_fast(s[2 * kk + 1][m][3]);
                union { short8 s8; uint32_t u[4]; } pa;
                asm("v_cvt_pk_bf16_f32 %0, %1, %2"
                    : "=v"(pa.u[0]) : "v"(p0), "v"(p1));
                asm("v_cvt_pk_bf16_f32 %0, %1, %2"
                    : "=v"(pa.u[1]) : "v"(p2), "v"(p3));
                asm("v_cvt_pk_bf16_f32 %0, %1, %2"
                    : "=v"(pa.u[2]) : "v"(p4), "v"(p5));
                asm("v_cvt_pk_bf16_f32 %0, %1, %2"
                    : "=v"(pa.u[3]) : "v"(p6), "v"(p7));
                acc[m][0] = __builtin_amdgcn_mfma_f32_16x16x32_bf16(
                    pa.s8, vreg[kk][0], acc[m][0], 0, 0, 0);
                acc[m][1] = __builtin_amdgcn_mfma_f32_16x16x32_bf16(
                    pa.s8, vreg[kk][1], acc[m][1], 0, 0, 0);
                asum[m] = __builtin_amdgcn_mfma_f32_16x16x32_bf16(
                    pa.s8, ones8, asum[m], 0, 0, 0);
            }
        }
    }

    // ---- epilogue: lane (fr,g) holds ctx[q=m*16+g*4+j][hd=n*16+fr];
    //      asum[m][j] is the matching row sum (same D layout) -> no shfl.
#pragma unroll
    for (int m = 0; m < 2; m++)
#pragma unroll
        for (int j = 0; j < 4; j++) {
            float inv = 1.f / asum[m][j];
#pragma unroll
            for (int n = 0; n < 2; n++) {
                size_t row = (size_t)b * SEQ + q0 + m * 16 + g * 4 + j;
                ctx[row * 256 + h * 32 + n * 16 + fr] =
                    f2bf(acc[m][n][j] * inv);
            }
        }
}

// ---------------------------------------------------------------------------
extern "C" void kernel_launch(void* const* d_in, const int* in_sizes, int n_in,
                              void* d_out, int out_size, void* d_ws,
                              size_t ws_size, hipStream_t stream) {
    const float* x   = (const float*)d_in[0];
    const float* wq  = (const float*)d_in[1];
    const float* wk  = (const float*)d_in[2];
    const float* wv  = (const float*)d_in[3];
    const float* g1  = (const float*)d_in[4];
    const float* be1 = (const float*)d_in[5];
    const float* g2  = (const float*)d_in[6];
    const float* be2 = (const float*)d_in[7];
    const float* wf1 = (const float*)d_in[8];
    const float* bf1 = (const float*)d_in[9];
    const float* wf2 = (const float*)d_in[10];
    const float* bf2 = (const float*)d_in[11];

    char* ws = (char*)d_ws;
    const size_t SZ16M = (size_t)ROWS * 256 * 2;  // 16 MiB
    ushort_t* wqkvT = (ushort_t*)(ws);                      // 768*256*2
    ushort_t* wf1T  = (ushort_t*)(ws + 393216);
    ushort_t* wf2T  = (ushort_t*)(ws + 524288);
    ushort_t* xn    = (ushort_t*)(ws + 655360);             // 16 MiB
    ushort_t* qonly = (ushort_t*)(ws + 655360 + SZ16M);     // 16 MiB
    ushort_t* kpk   = (ushort_t*)(ws + 655360 + 2 * SZ16M); // 16 MiB
    ushort_t* vpk   = (ushort_t*)(ws + 655360 + 3 * SZ16M); // 16 MiB
    ushort_t* ctxb  = (ushort_t*)(ws + 655360 + 4 * SZ16M); // 16 MiB
    ushort_t* ab    = (ushort_t*)(ws + 655360 + 5 * SZ16M); // 16 MiB

    ln1_prep<<<dim3(9472), dim3(256), 0, stream>>>(
        x, g1, be1, wq, wk, wv, wf1, wf2, xn, wqkvT, wf1T, wf2T);
    gemm_bt<3><<<dim3(256 * 6), dim3(256), 0, stream>>>(
        xn, wqkvT, (void*)qonly, nullptr, nullptr, kpk, vpk, 6, 256);
    attn_kernel<<<dim3(2048), dim3(256), 0, stream>>>(qonly, kpk, vpk, ctxb);
    ln2_kernel<<<dim3(ROWS / 4), dim3(256), 0, stream>>>(x, ctxb, g2, be2, ab);
    ffn_fused<<<dim3(512), dim3(256), 0, stream>>>(ab, wf1T, wf2T, bf1, bf2,
                                                   (float*)d_out);
}

// Round 17
// 118.091 us; speedup vs baseline: 1.0957x; 1.0014x over previous
//
#include <hip/hip_runtime.h>
#include <stdint.h>

typedef unsigned short ushort_t;
typedef __attribute__((ext_vector_type(8))) short short8;
typedef __attribute__((ext_vector_type(4))) float f32x4;
typedef __attribute__((ext_vector_type(4))) unsigned short ushort4v;

#define NBATCH 32
#define SEQ 1024
#define DIM 256
#define NH 8
#define ROWS (NBATCH * SEQ)   // 32768

__device__ __forceinline__ ushort_t f2bf(float f) {
    uint32_t u = __float_as_uint(f);
    u += 0x7fffu + ((u >> 16) & 1u);   // round-to-nearest-even
    return (ushort_t)(u >> 16);
}
__device__ __forceinline__ float bf2f(ushort_t h) {
    return __uint_as_float(((uint32_t)h) << 16);
}
__device__ __forceinline__ float exp2_fast(float x) {
    float r;
    asm("v_exp_f32 %0, %1" : "=v"(r) : "v"(x));
    return r;
}

typedef __attribute__((address_space(3))) void lds_void_t;
typedef const __attribute__((address_space(1))) void glob_void_t;
__device__ __forceinline__ void gld_lds16(const void* g, void* l) {
    __builtin_amdgcn_global_load_lds((glob_void_t*)g, (lds_void_t*)l, 16, 0, 0);
}

// ---------------------------------------------------------------------------
// Kernel 1: merged LN1 + weight prep (independent workloads, one launch).
// blocks [0, 8192): LayerNorm rows of x -> xn (bf16).
// blocks [8192, 9472): wT[n][k] = (bf16) w[k][n] for wq|wk|wv, wf1, wf2;
//   wq additionally scaled by log2(e) (softmax runs in exp2 domain).
// ---------------------------------------------------------------------------
__global__ __launch_bounds__(256) void ln1_prep(
    const float* __restrict__ x, const float* __restrict__ g,
    const float* __restrict__ beta, const float* __restrict__ wq,
    const float* __restrict__ wk, const float* __restrict__ wv,
    const float* __restrict__ wf1, const float* __restrict__ wf2,
    ushort_t* __restrict__ xn, ushort_t* __restrict__ wqkvT,
    ushort_t* __restrict__ wf1T, ushort_t* __restrict__ wf2T) {
    int blk = blockIdx.x;
    if (blk < 8192) {
        int wid = threadIdx.x >> 6, lane = threadIdx.x & 63;
        size_t row = (size_t)blk * 4 + wid;
        size_t base = row * 256 + lane * 4;
        float4 v = *(const float4*)(x + base);
        float s = v.x + v.y + v.z + v.w;
        float s2 = v.x * v.x + v.y * v.y + v.z * v.z + v.w * v.w;
#pragma unroll
        for (int msk = 1; msk < 64; msk <<= 1) {
            s += __shfl_xor(s, msk);
            s2 += __shfl_xor(s2, msk);
        }
        float mu = s * (1.f / 256.f);
        float var = s2 * (1.f / 256.f) - mu * mu;
        float rs = rsqrtf(var + 1e-5f);
        const float4 gv = *(const float4*)(g + lane * 4);
        const float4 bv = *(const float4*)(beta + lane * 4);
        ushort4v o;
        o[0] = f2bf((v.x - mu) * rs * gv.x + bv.x);
        o[1] = f2bf((v.y - mu) * rs * gv.y + bv.y);
        o[2] = f2bf((v.z - mu) * rs * gv.z + bv.z);
        o[3] = f2bf((v.w - mu) * rs * gv.w + bv.w);
        *(ushort4v*)(xn + base) = o;
    } else {
        int n = blk - 8192;
        int k = threadIdx.x;
        if (n < 768) {
            const float* w = (n < 256) ? wq : (n < 512 ? wk : wv);
            int nn = n & 255;
            float v = w[k * 256 + nn];
            if (n < 256) v *= 1.4426950408889634f;
            wqkvT[n * 256 + k] = f2bf(v);
        } else if (n < 1024) {
            int nn = n - 768;
            wf1T[nn * 256 + k] = f2bf(wf1[k * 256 + nn]);
        } else {
            int nn = n - 1024;
            wf2T[nn * 256 + k] = f2bf(wf2[k * 256 + nn]);
        }
    }
}

// ---------------------------------------------------------------------------
// Kernel 6: LayerNorm with +ctx residual (LN2)
// ---------------------------------------------------------------------------
__global__ __launch_bounds__(256) void ln2_kernel(
    const float* __restrict__ x, const ushort_t* __restrict__ ctx,
    const float* __restrict__ g, const float* __restrict__ beta,
    ushort_t* __restrict__ out) {
    int wid = threadIdx.x >> 6, lane = threadIdx.x & 63;
    size_t row = (size_t)blockIdx.x * 4 + wid;
    size_t base = row * 256 + lane * 4;
    float4 v = *(const float4*)(x + base);
    ushort4v c = *(const ushort4v*)(ctx + base);
    v.x += bf2f(c[0]); v.y += bf2f(c[1]);
    v.z += bf2f(c[2]); v.w += bf2f(c[3]);
    float s  = v.x + v.y + v.z + v.w;
    float s2 = v.x * v.x + v.y * v.y + v.z * v.z + v.w * v.w;
#pragma unroll
    for (int msk = 1; msk < 64; msk <<= 1) {
        s  += __shfl_xor(s, msk);
        s2 += __shfl_xor(s2, msk);
    }
    float mu  = s * (1.f / 256.f);
    float var = s2 * (1.f / 256.f) - mu * mu;
    float rs  = rsqrtf(var + 1e-5f);
    const float4 gv = *(const float4*)(g + lane * 4);
    const float4 bv = *(const float4*)(beta + lane * 4);
    ushort4v o;
    o[0] = f2bf((v.x - mu) * rs * gv.x + bv.x);
    o[1] = f2bf((v.y - mu) * rs * gv.y + bv.y);
    o[2] = f2bf((v.z - mu) * rs * gv.z + bv.z);
    o[3] = f2bf((v.w - mu) * rs * gv.w + bv.w);
    *(ushort4v*)(out + base) = o;
}

// ---------------------------------------------------------------------------
// Kernel 3: QKV GEMM (R13 text, BK=32 — R14's BK=64 regressed, reverted).
// C[M x N] = A[M x 256] @ B^T[N x 256]^T  (bf16, fp32 acc), XCD swizzle.
// EPI=3: Q -> Cp (ldc=256); K/V -> fragment-packed kpk/vpk blobs so attn's
// wave-loads are single coalesced 1KB segments (sigma-permuted V, see R13).
// ---------------------------------------------------------------------------
template <int EPI>
__global__ __launch_bounds__(256) void gemm_bt(
    const ushort_t* __restrict__ A, const ushort_t* __restrict__ B,
    void* __restrict__ Cp, const float* __restrict__ bias,
    const ushort_t* __restrict__ res, ushort_t* __restrict__ kout,
    ushort_t* __restrict__ vout, int nbn, int ldc) {
    __shared__ ushort_t lds_a[4096];  // [128][32]
    __shared__ ushort_t lds_b[4096];  // [128][32] (rows = output cols)
    int cpx = gridDim.x >> 3;
    int blk = (blockIdx.x & 7) * cpx + (blockIdx.x >> 3);
    int bn = blk % nbn, bm = blk / nbn;
    int m0 = bm * 128, n0 = bn * 128;
    int tid = threadIdx.x, wid = tid >> 6, lane = tid & 63;
    int fr = lane & 15, g = lane >> 4;
    int wm = (wid >> 1) * 64, wn = (wid & 1) * 64;

    f32x4 acc[4][4];
    const f32x4 fz = {0.f, 0.f, 0.f, 0.f};
#pragma unroll
    for (int m = 0; m < 4; m++)
#pragma unroll
        for (int n = 0; n < 4; n++) acc[m][n] = fz;

    for (int kt = 0; kt < 256; kt += 32) {
#pragma unroll
        for (int i = 0; i < 2; i++) {
            const ushort_t* as =
                A + (size_t)(m0 + i * 64 + (tid >> 2)) * 256 + kt + (tid & 3) * 8;
            gld_lds16(as, &lds_a[i * 2048 + wid * 512]);
            const ushort_t* bs =
                B + (size_t)(n0 + i * 64 + (tid >> 2)) * 256 + kt + (tid & 3) * 8;
            gld_lds16(bs, &lds_b[i * 2048 + wid * 512]);
        }
        __syncthreads();
        short8 af[4], bfr[4];
#pragma unroll
        for (int m = 0; m < 4; m++)
            af[m] = *(const short8*)&lds_a[(wm + m * 16 + fr) * 32 + g * 8];
#pragma unroll
        for (int n = 0; n < 4; n++)
            bfr[n] = *(const short8*)&lds_b[(wn + n * 16 + fr) * 32 + g * 8];
#pragma unroll
        for (int m = 0; m < 4; m++)
#pragma unroll
            for (int n = 0; n < 4; n++)
                acc[m][n] = __builtin_amdgcn_mfma_f32_16x16x32_bf16(
                    af[m], bfr[n], acc[m][n], 0, 0, 0);
        __syncthreads();
    }

#pragma unroll
    for (int m = 0; m < 4; m++)
#pragma unroll
        for (int n = 0; n < 4; n++) {
            int col = n0 + wn + n * 16 + fr;
            int rowbase = m0 + wm + m * 16 + g * 4;
            if (EPI == 3 && col >= 512) {
                // V: fragment-packed, sigma-permuted (j=0..3 -> one 8B store)
                int hh = (col >> 5) & 7, hd = col & 31;
                int nn = hd >> 4, frv = hd & 15;
                int bb = rowbase >> 10;
                int key = rowbase & 1023;  // multiple of 4
                int slot0 = (key & ~31) + (((key & 15) >> 2) << 3) +
                            (((key >> 4) & 1) << 2);
                int t64 = slot0 >> 6, kk = (slot0 & 63) >> 5;
                int gv = (slot0 & 31) >> 3, e0 = slot0 & 7;
                ushort4v o;
                o[0] = f2bf(acc[m][n][0]);
                o[1] = f2bf(acc[m][n][1]);
                o[2] = f2bf(acc[m][n][2]);
                o[3] = f2bf(acc[m][n][3]);
                *(ushort4v*)(vout + (size_t)(bb * 8 + hh) * 32768 + t64 * 2048 +
                             (kk * 2 + nn) * 512 + (gv * 16 + frv) * 8 + e0) = o;
            } else if (EPI == 3 && col >= 256) {
                // K: fragment-packed scalar stores (16B apart across j)
                int hh = (col >> 5) & 7, hd = col & 31;
                int gk = hd >> 3, e = hd & 7;
                int bb = rowbase >> 10;
                int s = rowbase & 1023;  // key base; (s>>4) const across j
                size_t base = (size_t)(bb * 8 + hh) * 32768 + (s >> 4) * 512 +
                              gk * 128 + e;
#pragma unroll
                for (int j = 0; j < 4; j++)
                    kout[base + ((s & 15) + j) * 8] = f2bf(acc[m][n][j]);
            } else {
                float bv = (EPI == 1 || EPI == 2) ? bias[col] : 0.f;
#pragma unroll
                for (int j = 0; j < 4; j++) {
                    size_t row = (size_t)(rowbase + j);
                    float v = acc[m][n][j] + bv;
                    if (EPI == 1) v = fmaxf(v, 0.f);
                    if (EPI == 2) {
                        v += bf2f(res[row * 256 + col]);
                        ((float*)Cp)[row * ldc + col] = v;
                    } else {
                        ((ushort_t*)Cp)[row * ldc + col] = f2bf(v);
                    }
                }
            }
        }
}

// ---------------------------------------------------------------------------
// Kernel 7: fused FFN — out = a + relu(a@W1+b1)@W2 + b2, one 64-row stripe
// per block. Phase 1 keeps h_tile in padded LDS ([64][264]: stride 528B ->
// 2-way max on phase-2 reads); phase 2 consumes it as the A-operand.
// Eliminates h's 32MB global round-trip + the ab re-read + one launch.
// (R16's attempt to also fuse LN2 in as phase 0 produced timing-dependent
// nondeterminism + was slower — reverted; LN2 stays a separate kernel.)
// ---------------------------------------------------------------------------
__global__ __launch_bounds__(256) void ffn_fused(
    const ushort_t* __restrict__ A, const ushort_t* __restrict__ W1,
    const ushort_t* __restrict__ W2, const float* __restrict__ b1,
    const float* __restrict__ b2, float* __restrict__ out) {
    __shared__ ushort_t a_lds[64 * 32];    //  4 KB
    __shared__ ushort_t w_lds[256 * 32];   // 16 KB (W1 then W2 staging)
    __shared__ ushort_t h_lds[64 * 264];   // 33 KB padded
    int m0 = blockIdx.x * 64;
    int tid = threadIdx.x, wid = tid >> 6, lane = tid & 63;
    int fr = lane & 15, g = lane >> 4;
    int wn = wid * 64;  // this wave's output-column block (both phases)

    f32x4 acc[4][4];
    const f32x4 fz = {0.f, 0.f, 0.f, 0.f};
#pragma unroll
    for (int m = 0; m < 4; m++)
#pragma unroll
        for (int n = 0; n < 4; n++) acc[m][n] = fz;

    // ---------------- phase 1: h = relu(a @ W1^T + b1) -> h_lds ----------
    for (int kt = 0; kt < 256; kt += 32) {
        gld_lds16(A + (size_t)(m0 + (tid >> 2)) * 256 + kt + (tid & 3) * 8,
                  &a_lds[wid * 512]);
#pragma unroll
        for (int i = 0; i < 4; i++)
            gld_lds16(W1 + (size_t)(i * 64 + (tid >> 2)) * 256 + kt +
                          (tid & 3) * 8,
                      &w_lds[i * 2048 + wid * 512]);
        __syncthreads();
        short8 af[4], bfr[4];
#pragma unroll
        for (int m = 0; m < 4; m++)
            af[m] = *(const short8*)&a_lds[(m * 16 + fr) * 32 + g * 8];
#pragma unroll
        for (int n = 0; n < 4; n++)
            bfr[n] = *(const short8*)&w_lds[(wn + n * 16 + fr) * 32 + g * 8];
#pragma unroll
        for (int m = 0; m < 4; m++)
#pragma unroll
            for (int n = 0; n < 4; n++)
                acc[m][n] = __builtin_amdgcn_mfma_f32_16x16x32_bf16(
                    af[m], bfr[n], acc[m][n], 0, 0, 0);
        __syncthreads();
    }
#pragma unroll
    for (int m = 0; m < 4; m++)
#pragma unroll
        for (int n = 0; n < 4; n++) {
            int col = wn + n * 16 + fr;
            float bv = b1[col];
#pragma unroll
            for (int j = 0; j < 4; j++) {
                int row = m * 16 + g * 4 + j;
                h_lds[row * 264 + col] = f2bf(fmaxf(acc[m][n][j] + bv, 0.f));
            }
            acc[m][n] = fz;  // re-zero for phase 2
        }
    __syncthreads();

    // ---------------- phase 2: out = a + h @ W2^T + b2 --------------------
    for (int kt = 0; kt < 256; kt += 32) {
#pragma unroll
        for (int i = 0; i < 4; i++)
            gld_lds16(W2 + (size_t)(i * 64 + (tid >> 2)) * 256 + kt +
                          (tid & 3) * 8,
                      &w_lds[i * 2048 + wid * 512]);
        __syncthreads();
        short8 af[4], bfr[4];
#pragma unroll
        for (int m = 0; m < 4; m++)
            af[m] = *(const short8*)&h_lds[(m * 16 + fr) * 264 + kt + g * 8];
#pragma unroll
        for (int n = 0; n < 4; n++)
            bfr[n] = *(const short8*)&w_lds[(wn + n * 16 + fr) * 32 + g * 8];
#pragma unroll
        for (int m = 0; m < 4; m++)
#pragma unroll
            for (int n = 0; n < 4; n++)
                acc[m][n] = __builtin_amdgcn_mfma_f32_16x16x32_bf16(
                    af[m], bfr[n], acc[m][n], 0, 0, 0);
        __syncthreads();
    }
#pragma unroll
    for (int m = 0; m < 4; m++)
#pragma unroll
        for (int n = 0; n < 4; n++) {
            int col = wn + n * 16 + fr;
            float bv = b2[col];
#pragma unroll
            for (int j = 0; j < 4; j++) {
                size_t row = (size_t)(m0 + m * 16 + g * 4 + j);
                out[row * 256 + col] =
                    acc[m][n][j] + bv + bf2f(A[row * 256 + col]);
            }
        }
}

// ---------------------------------------------------------------------------
// Kernel 5: flash attention, swapped-QK^T, zero LDS, branch-free & shfl-free.
// FROZEN at R13 text (5 data-movement restructures now failed; address-only
// changes proven safe). K/V from fragment-packed blobs: every wave-load is
// one contiguous 1KB segment (base + lane*16B).
// ---------------------------------------------------------------------------
__global__ __launch_bounds__(256, 4) void attn_kernel(
    const ushort_t* __restrict__ q, const ushort_t* __restrict__ kpk,
    const ushort_t* __restrict__ vpk, ushort_t* __restrict__ ctx) {
    int cpx = gridDim.x >> 3;
    int wgid = (blockIdx.x & 7) * cpx + (blockIdx.x >> 3);
    int bh = wgid >> 3, qt = wgid & 7;
    int b = bh >> 3, h = bh & 7;
    int tid = threadIdx.x, wid = tid >> 6, lane = tid & 63;
    int fr = lane & 15, g = lane >> 4;
    int q0 = qt * 128 + wid * 32;
    const ushort_t* qbase = q + (size_t)b * SEQ * 256;
    const ushort_t* kpb = kpk + (size_t)bh * 32768;
    const ushort_t* vpb = vpk + (size_t)bh * 32768;
    const int l8 = lane * 8;

    // Q fragments (B operand of swapped QK^T); Q pre-scaled by log2(e)
    short8 qb[2];
#pragma unroll
    for (int m = 0; m < 2; m++)
        qb[m] = *(const short8*)(qbase + (size_t)(q0 + m * 16 + fr) * 256 +
                                 h * 32 + g * 8);

    f32x4 acc[2][2], asum[2];
    const f32x4 fz = {0.f, 0.f, 0.f, 0.f};
#pragma unroll
    for (int m = 0; m < 2; m++) {
        acc[m][0] = fz;
        acc[m][1] = fz;
        asum[m] = fz;
    }
    // all-ones bf16 B-fragment for the row-sum MFMA
    short8 ones8;
#pragma unroll
    for (int i = 0; i < 8; i++) ones8[i] = (short)0x3f80;

    // prefetch first K tile (64 keys = 4 fragments; coalesced 1KB each)
    short8 kreg[4];
#pragma unroll
    for (int n = 0; n < 4; n++)
        kreg[n] = *(const short8*)(kpb + n * 512 + l8);

    for (int kv = 0; kv < SEQ; kv += 64) {
        // ---- issue V loads for this tile (coalesced; in flight through QK)
        short8 vreg[2][2];
#pragma unroll
        for (int kk = 0; kk < 2; kk++) {
            vreg[kk][0] =
                *(const short8*)(vpb + (kv >> 6) * 2048 + (kk * 2) * 512 + l8);
            vreg[kk][1] = *(const short8*)(vpb + (kv >> 6) * 2048 +
                                           (kk * 2 + 1) * 512 + l8);
        }

        // ---- scores (log2 domain): s[n][m][j] = S[key=n*16+g*4+j][q=m*16+fr]
        f32x4 s[4][2];
#pragma unroll
        for (int n = 0; n < 4; n++)
#pragma unroll
            for (int m = 0; m < 2; m++)
                s[n][m] = __builtin_amdgcn_mfma_f32_16x16x32_bf16(kreg[n], qb[m],
                                                                  fz, 0, 0, 0);

        // ---- prefetch next K tile (completes during exp + PV)
        if (kv + 64 < SEQ) {
#pragma unroll
            for (int n = 0; n < 4; n++)
                kreg[n] = *(const short8*)(kpb + ((kv + 64) >> 4) * 512 +
                                           n * 512 + l8);
        }

        // ---- P = exp2(s), pack to bf16 in-lane, PV + ones-column row-sum
#pragma unroll
        for (int kk = 0; kk < 2; kk++) {
#pragma unroll
            for (int m = 0; m < 2; m++) {
                float p0 = exp2_fast(s[2 * kk][m][0]);
                float p1 = exp2_fast(s[2 * kk][m][1]);
                float p2 = exp2_fast(s[2 * kk][m][2]);
                float p3 = exp2_fast(s[2 * kk][m][3]);
                float p4 = exp2_fast(s[2 * kk + 1][m][0]);
                float p5 = exp2_fast(s[2 * kk + 1][m][1]);
                float p6 = exp2_fast(s[2 * kk + 1][m][2]);
                float p7 = exp2_fast(s[2 * kk + 1][m][3]);
                union { short8 s8; uint32_t u[4]; } pa;
                asm("v_cvt_pk_bf16_f32 %0, %1, %2"
                    : "=v"(pa.u[0]) : "v"(p0), "v"(p1));
                asm("v_cvt_pk_bf16_f32 %0, %1, %2"
                    : "=v"(pa.u[1]) : "v"(p2), "v"(p3));
                asm("v_cvt_pk_bf16_f32 %0, %1, %2"
                    : "=v"(pa.u[2]) : "v"(p4), "v"(p5));
                asm("v_cvt_pk_bf16_f32 %0, %1, %2"
                    : "=v"(pa.u[3]) : "v"(p6), "v"(p7));
                acc[m][0] = __builtin_amdgcn_mfma_f32_16x16x32_bf16(
                    pa.s8, vreg[kk][0], acc[m][0], 0, 0, 0);
                acc[m][1] = __builtin_amdgcn_mfma_f32_16x16x32_bf16(
                    pa.s8, vreg[kk][1], acc[m][1], 0, 0, 0);
                asum[m] = __builtin_amdgcn_mfma_f32_16x16x32_bf16(
                    pa.s8, ones8, asum[m], 0, 0, 0);
            }
        }
    }

    // ---- epilogue: lane (fr,g) holds ctx[q=m*16+g*4+j][hd=n*16+fr];
    //      asum[m][j] is the matching row sum (same D layout) -> no shfl.
#pragma unroll
    for (int m = 0; m < 2; m++)
#pragma unroll
        for (int j = 0; j < 4; j++) {
            float inv = 1.f / asum[m][j];
#pragma unroll
            for (int n = 0; n < 2; n++) {
                size_t row = (size_t)b * SEQ + q0 + m * 16 + g * 4 + j;
                ctx[row * 256 + h * 32 + n * 16 + fr] =
                    f2bf(acc[m][n][j] * inv);
            }
        }
}

// ---------------------------------------------------------------------------
extern "C" void kernel_launch(void* const* d_in, const int* in_sizes, int n_in,
                              void* d_out, int out_size, void* d_ws,
                              size_t ws_size, hipStream_t stream) {
    const float* x   = (const float*)d_in[0];
    const float* wq  = (const float*)d_in[1];
    const float* wk  = (const float*)d_in[2];
    const float* wv  = (const float*)d_in[3];
    const float* g1  = (const float*)d_in[4];
    const float* be1 = (const float*)d_in[5];
    const float* g2  = (const float*)d_in[6];
    const float* be2 = (const float*)d_in[7];
    const float* wf1 = (const float*)d_in[8];
    const float* bf1 = (const float*)d_in[9];
    const float* wf2 = (const float*)d_in[10];
    const float* bf2 = (const float*)d_in[11];

    char* ws = (char*)d_ws;
    const size_t SZ16M = (size_t)ROWS * 256 * 2;  // 16 MiB
    ushort_t* wqkvT = (ushort_t*)(ws);                      // 768*256*2
    ushort_t* wf1T  = (ushort_t*)(ws + 393216);
    ushort_t* wf2T  = (ushort_t*)(ws + 524288);
    ushort_t* xn    = (ushort_t*)(ws + 655360);             // 16 MiB
    ushort_t* qonly = (ushort_t*)(ws + 655360 + SZ16M);     // 16 MiB
    ushort_t* kpk   = (ushort_t*)(ws + 655360 + 2 * SZ16M); // 16 MiB
    ushort_t* vpk   = (ushort_t*)(ws + 655360 + 3 * SZ16M); // 16 MiB
    ushort_t* ctxb  = (ushort_t*)(ws + 655360 + 4 * SZ16M); // 16 MiB
    ushort_t* ab    = (ushort_t*)(ws + 655360 + 5 * SZ16M); // 16 MiB

    ln1_prep<<<dim3(9472), dim3(256), 0, stream>>>(
        x, g1, be1, wq, wk, wv, wf1, wf2, xn, wqkvT, wf1T, wf2T);
    gemm_bt<3><<<dim3(256 * 6), dim3(256), 0, stream>>>(
        xn, wqkvT, (void*)qonly, nullptr, nullptr, kpk, vpk, 6, 256);
    attn_kernel<<<dim3(2048), dim3(256), 0, stream>>>(qonly, kpk, vpk, ctxb);
    ln2_kernel<<<dim3(ROWS / 4), dim3(256), 0, stream>>>(x, ctxb, g2, be2, ab);
    ffn_fused<<<dim3(512), dim3(256), 0, stream>>>(ab, wf1T, wf2T, bf1, bf2,
                                                   (float*)d_out);
}